// Round 3
// baseline (3227.924 us; speedup 1.0000x reference)
//
#include <hip/hip_runtime.h>
#include <math.h>

#define NB       8
#define SEQ      8192
#define L1OUT    2048
#define LOUT     1024
#define DMODEL   256
#define DINNER   1024
#define NHEADS   16
#define HEADDIM  64
#define DSTATE   64
#define CONVDIM  1152
#define DINPROJ  2192
#define NPADIN   2304     // in_proj rows padded to multiple of 128
#define NLAYERS  8

typedef _Float16 f16;
typedef __attribute__((ext_vector_type(8))) _Float16 f16x8;
typedef __attribute__((ext_vector_type(4))) _Float16 f16x4;
typedef __attribute__((ext_vector_type(4))) float    f32x4;

__device__ __forceinline__ float gelu_f(float v) {
    return 0.5f * v * (1.0f + erff(v * 0.70710678118654752f));
}
__device__ __forceinline__ float silu_f(float v) {
    return v / (1.0f + expf(-v));
}

__device__ __forceinline__ void gload16(const void* g, void* l) {
    __builtin_amdgcn_global_load_lds(
        (const __attribute__((address_space(1))) unsigned int*)g,
        (__attribute__((address_space(3))) unsigned int*)l, 16, 0, 0);
}

// ---------------- weight casts ----------------
__global__ __launch_bounds__(256) void k_cast(const float* __restrict__ in,
                                              f16* __restrict__ out, int n) {
    int i = blockIdx.x * 256 + threadIdx.x;
    if (i < n) out[i] = (f16)in[i];
}

// in_proj: [8][2192][256] fp32 -> [8][2304][256] f16, zero-padded rows
__global__ __launch_bounds__(256) void k_cast_inproj(const float* __restrict__ w,
                                                     f16* __restrict__ out) {
    int idx = blockIdx.x * 256 + threadIdx.x;       // 8*2304*256
    int c = idx & 255;
    int r = (idx >> 8) % NPADIN;
    int l = idx / (NPADIN * 256);
    float v = (r < DINPROJ) ? w[((size_t)l * DINPROJ + r) * 256 + c] : 0.f;
    out[idx] = (f16)v;
}

// ---------------- conv1 (3->64, k16, s4, pad6) + GELU ----------------
__global__ __launch_bounds__(256) void k_conv1(const float* __restrict__ x,
                                               const float* __restrict__ w,
                                               const float* __restrict__ bias,
                                               float* __restrict__ out) {
    int idx = blockIdx.x * 256 + threadIdx.x;      // NB*64*L1OUT
    int t  = idx & (L1OUT - 1);
    int co = (idx >> 11) & 63;
    int b  = idx >> 17;
    float s = bias[co];
#pragma unroll
    for (int ci = 0; ci < 3; ++ci) {
        const float* xp = x + ((size_t)b * 3 + ci) * SEQ;
        const float* wp = w + (co * 3 + ci) * 16;
#pragma unroll
        for (int k = 0; k < 16; ++k) {
            int pos = t * 4 + k - 6;
            if (pos >= 0 && pos < SEQ) s = fmaf(xp[pos], wp[k], s);
        }
    }
    out[idx] = gelu_f(s);
}

// ---------------- im2col for conv2 (64ch, k16, s2, pad7) -> f16 ----------------
__global__ __launch_bounds__(256) void k_im2col(const float* __restrict__ h1,
                                                f16* __restrict__ A) {
    int idx = blockIdx.x * 256 + threadIdx.x;      // 8192*1024
    int col = idx & 1023;
    int row = idx >> 10;
    int t = row & (LOUT - 1);
    int b = row >> 10;
    int ci = col >> 4, k = col & 15;
    int pos = t * 2 + k - 7;
    float v = 0.f;
    if (pos >= 0 && pos < L1OUT) v = h1[((size_t)b * 64 + ci) * L1OUT + pos];
    A[idx] = (f16)v;
}

// ---------------- fp16 MFMA GEMM: C[M,N] = A[M,K] * B[Npad,K]^T ----------------
template<int BM, int EPI>
__global__ __launch_bounds__(256) void k_hgemm(const f16* __restrict__ A,
                                               const f16* __restrict__ Bw,
                                               float* __restrict__ Cf,
                                               f16* __restrict__ Ch,
                                               int M, int N, int K,
                                               const float* __restrict__ bias) {
    constexpr int MI = BM / 32;
    __shared__ f16 As[BM * 32];
    __shared__ f16 Bs[128 * 32];
    int tid  = threadIdx.x;
    int lane = tid & 63, wid = tid >> 6;
    int wm = wid >> 1, wn = wid & 1;
    int row0 = blockIdx.y * BM, col0 = blockIdx.x * 128;
    int lr = lane & 15, kb = lane >> 4;

    f32x4 acc[MI][4];
#pragma unroll
    for (int mi = 0; mi < MI; ++mi)
#pragma unroll
        for (int ni = 0; ni < 4; ++ni)
            acc[mi][ni] = (f32x4){0.f, 0.f, 0.f, 0.f};

    int srow = tid >> 2;
    int scol = (tid & 3) * 8;

    for (int k0 = 0; k0 < K; k0 += 32) {
        __syncthreads();
#pragma unroll
        for (int is = 0; is < BM / 64; ++is)
            gload16(A + (size_t)(row0 + is * 64 + srow) * K + k0 + scol,
                    &As[is * 2048 + wid * 512]);
#pragma unroll
        for (int is = 0; is < 2; ++is)
            gload16(Bw + (size_t)(col0 + is * 64 + srow) * K + k0 + scol,
                    &Bs[is * 2048 + wid * 512]);
        __syncthreads();

        f16x8 a[MI], b[4];
#pragma unroll
        for (int mi = 0; mi < MI; ++mi)
            a[mi] = *reinterpret_cast<const f16x8*>(
                &As[(wm * (BM / 2) + mi * 16 + lr) * 32 + kb * 8]);
#pragma unroll
        for (int ni = 0; ni < 4; ++ni)
            b[ni] = *reinterpret_cast<const f16x8*>(
                &Bs[(wn * 64 + ni * 16 + lr) * 32 + kb * 8]);
#pragma unroll
        for (int mi = 0; mi < MI; ++mi)
#pragma unroll
            for (int ni = 0; ni < 4; ++ni)
                acc[mi][ni] = __builtin_amdgcn_mfma_f32_16x16x32_f16(
                    a[mi], b[ni], acc[mi][ni], 0, 0, 0);
    }

#pragma unroll
    for (int mi = 0; mi < MI; ++mi)
#pragma unroll
        for (int ni = 0; ni < 4; ++ni) {
            int ccol = col0 + wn * 64 + ni * 16 + lr;
            if (ccol < N) {
                int rbase = row0 + wm * (BM / 2) + mi * 16 + kb * 4;
                f32x4 v = acc[mi][ni];
#pragma unroll
                for (int r = 0; r < 4; ++r) {
                    float val = v[r];
                    if (EPI == 1) val = gelu_f(val + bias[ccol]);
                    if (Cf) Cf[(size_t)(rbase + r) * N + ccol] = val;
                    if (Ch) Ch[(size_t)(rbase + r) * N + ccol] = (f16)val;
                }
            }
        }
}

// ---------------- depthwise causal conv (k=4) + SiLU on xBC ----------------
__global__ __launch_bounds__(256) void k_dwconv(const float* __restrict__ zx,
                                                const float* __restrict__ w,
                                                const float* __restrict__ bias,
                                                float* __restrict__ out) {
    int idx = blockIdx.x * 256 + threadIdx.x;      // NB*LOUT*CONVDIM
    int c  = idx % CONVDIM;
    int bl = idx / CONVDIM;
    int l  = bl & (LOUT - 1);
    const float* wp = w + c * 4;
    float s = bias[c];
#pragma unroll
    for (int k = 0; k < 4; ++k) {
        int t = l - 3 + k;
        if (t >= 0) s = fmaf(zx[(size_t)(bl - 3 + k) * DINPROJ + DINNER + c], wp[k], s);
    }
    out[idx] = silu_f(s);
}

// -------- dadt[bl,h] = (exp(-exp(A_log)*dt), dt) interleaved float2 --------
__global__ __launch_bounds__(256) void k_dt(const float* __restrict__ zx,
                                            const float* __restrict__ dt_bias,
                                            const float* __restrict__ A_log,
                                            float* __restrict__ dadt) {
    int idx = blockIdx.x * 256 + threadIdx.x;      // NB*LOUT*NHEADS
    int hh = idx & 15;
    int bl = idx >> 4;
    float raw = zx[(size_t)bl * DINPROJ + DINNER + CONVDIM + hh] + dt_bias[hh];
    float dtv = (raw > 20.f) ? raw : log1pf(expf(raw));
    float dav = expf(-expf(A_log[hh]) * dtv);
    *(float2*)&dadt[(size_t)idx * 2] = make_float2(dav, dtv);
}

// ---------------- selective scan: no LDS, no barriers ----------------
// grid: NB*NHEADS*8 blocks of 64 threads (1 wave).
// block = (b, hh, pq): p rows [pq*8, pq*8+8).
// lane: pr = tid>>3 -> p = pq*8+pr ; ng = tid&7 -> n in [ng*8, ng*8+8)
// register-double-buffered 4-step prefetch groups, direct global loads.
__global__ __launch_bounds__(64) void k_scan(const float* __restrict__ xbc,
                                             const float* __restrict__ dadt,
                                             float* __restrict__ yout) {
    int tid = threadIdx.x;
    int bid = blockIdx.x;
    int pq = bid & 7, hh = (bid >> 3) & 15, b = bid >> 7;
    int pr = tid >> 3, ng = tid & 7;
    size_t base = (size_t)b * LOUT;

    const float* pB = xbc + base * CONVDIM + DINNER + ng * 8;
    const float* pC = pB + DSTATE;
    const float* pX = xbc + base * CONVDIM + hh * 64 + pq * 8 + pr;
    const float* pA = dadt + (base * NHEADS + hh) * 2;
    float* pY = yout + base * DINNER + hh * 64 + pq * 8 + pr;

    float h[8];
#pragma unroll
    for (int j = 0; j < 8; ++j) h[j] = 0.f;

    float4 vB0[2][4], vB1[2][4], vC0[2][4], vC1[2][4];
    float  vX[2][4];
    float2 vA[2][4];

#define LOADG(BUF, G)                                                        \
    {                                                                        \
        _Pragma("unroll")                                                    \
        for (int s = 0; s < 4; ++s) {                                        \
            int t = (G) * 4 + s;                                             \
            size_t r = (size_t)t * CONVDIM;                                  \
            vB0[BUF][s] = *(const float4*)(pB + r);                          \
            vB1[BUF][s] = *(const float4*)(pB + r + 4);                      \
            vC0[BUF][s] = *(const float4*)(pC + r);                          \
            vC1[BUF][s] = *(const float4*)(pC + r + 4);                      \
            vX[BUF][s]  = pX[r];                                             \
            vA[BUF][s]  = *(const float2*)(pA + (size_t)t * NHEADS * 2);     \
        }                                                                    \
    }

#define COMPG(BUF, G)                                                        \
    {                                                                        \
        _Pragma("unroll")                                                    \
        for (int s = 0; s < 4; ++s) {                                        \
            float dAv = vA[BUF][s].x, dtv = vA[BUF][s].y;                    \
            float cc = dtv * vX[BUF][s];                                     \
            float bb[8] = {vB0[BUF][s].x, vB0[BUF][s].y, vB0[BUF][s].z,      \
                           vB0[BUF][s].w, vB1[BUF][s].x, vB1[BUF][s].y,      \
                           vB1[BUF][s].z, vB1[BUF][s].w};                    \
            float cv[8] = {vC0[BUF][s].x, vC0[BUF][s].y, vC0[BUF][s].z,      \
                           vC0[BUF][s].w, vC1[BUF][s].x, vC1[BUF][s].y,      \
                           vC1[BUF][s].z, vC1[BUF][s].w};                    \
            float ys = 0.f;                                                  \
            _Pragma("unroll")                                                \
            for (int j = 0; j < 8; ++j) {                                    \
                h[j] = fmaf(h[j], dAv, cc * bb[j]);                          \
                ys = fmaf(h[j], cv[j], ys);                                  \
            }                                                                \
            ys += __shfl_xor(ys, 1);                                         \
            ys += __shfl_xor(ys, 2);                                         \
            ys += __shfl_xor(ys, 4);                                         \
            if (ng == 0) pY[(size_t)((G) * 4 + s) * DINNER] = ys;            \
        }                                                                    \
    }

    LOADG(0, 0);
    for (int gg = 0; gg < 128; ++gg) {
        int g = gg * 2;
        LOADG(1, g + 1);
        COMPG(0, g);
        if (gg < 127) LOADG(0, g + 2);
        COMPG(1, g + 1);
    }
#undef LOADG
#undef COMPG
}

// ------ y = (yss + D*xh) * silu(z); RMSNorm * rms_w; write f16 for out_proj ----
__global__ __launch_bounds__(256) void k_gate(const float* __restrict__ zx,
                                              const float* __restrict__ xbc,
                                              const float* __restrict__ ssmD,
                                              const float* __restrict__ rmsw,
                                              const float* __restrict__ y,
                                              f16* __restrict__ ygate) {
    __shared__ float sh[4];
    int bl = blockIdx.x, tid = threadIdx.x;
    int c = tid * 4;
    float4 ys = *reinterpret_cast<const float4*>(&y[(size_t)bl * DINNER + c]);
    float4 xh = *reinterpret_cast<const float4*>(&xbc[(size_t)bl * CONVDIM + c]);
    float4 z4 = *reinterpret_cast<const float4*>(&zx[(size_t)bl * DINPROJ + c]);
    float Dv = ssmD[tid >> 4];
    float v[4] = {ys.x, ys.y, ys.z, ys.w};
    float xv[4] = {xh.x, xh.y, xh.z, xh.w};
    float zv[4] = {z4.x, z4.y, z4.z, z4.w};
    float ss = 0.f;
#pragma unroll
    for (int j = 0; j < 4; ++j) {
        v[j] = (v[j] + Dv * xv[j]) * silu_f(zv[j]);
        ss += v[j] * v[j];
    }
    int lane = tid & 63, wid = tid >> 6;
#pragma unroll
    for (int o = 32; o > 0; o >>= 1) ss += __shfl_down(ss, o, 64);
    if (lane == 0) sh[wid] = ss;
    __syncthreads();
    float total = sh[0] + sh[1] + sh[2] + sh[3];
    float r = rsqrtf(total * (1.f / DINNER) + 1e-5f);
    f16x4 o4;
    o4.x = (f16)(v[0] * r * rmsw[c + 0]);
    o4.y = (f16)(v[1] * r * rmsw[c + 1]);
    o4.z = (f16)(v[2] * r * rmsw[c + 2]);
    o4.w = (f16)(v[3] * r * rmsw[c + 3]);
    *reinterpret_cast<f16x4*>(&ygate[(size_t)bl * DINNER + c]) = o4;
}

// ---------------- final LayerNorm + mean pool (atomics) ----------------
__global__ __launch_bounds__(256) void k_lnpool(const float* __restrict__ h,
                                                const float* __restrict__ lnw,
                                                const float* __restrict__ lnb,
                                                float* __restrict__ pooled) {
    __shared__ float sh1[4], sh2[4];
    int bl = blockIdx.x, c = threadIdx.x;
    float v = h[(size_t)bl * DMODEL + c];
    float s1 = v, s2 = v * v;
    int lane = c & 63, wid = c >> 6;
#pragma unroll
    for (int o = 32; o > 0; o >>= 1) {
        s1 += __shfl_down(s1, o, 64);
        s2 += __shfl_down(s2, o, 64);
    }
    if (lane == 0) { sh1[wid] = s1; sh2[wid] = s2; }
    __syncthreads();
    float t1 = sh1[0] + sh1[1] + sh1[2] + sh1[3];
    float t2 = sh2[0] + sh2[1] + sh2[2] + sh2[3];
    float mu = t1 * (1.f / DMODEL);
    float var = t2 * (1.f / DMODEL) - mu * mu;
    float o = (v - mu) * rsqrtf(var + 1e-5f) * lnw[c] + lnb[c];
    atomicAdd(&pooled[(bl >> 10) * DMODEL + c], o * (1.f / LOUT));
}

__global__ void k_zero(float* __restrict__ p, int n) {
    int i = blockIdx.x * 256 + threadIdx.x;
    if (i < n) p[i] = 0.f;
}

// ---------------- regression head ----------------
__global__ __launch_bounds__(128) void k_head(const float* __restrict__ pooled,
                                              const float* __restrict__ w1,
                                              const float* __restrict__ b1,
                                              const float* __restrict__ w2,
                                              const float* __restrict__ b2,
                                              float* __restrict__ out) {
    __shared__ float red[2];
    int b = blockIdx.x, j = threadIdx.x;
    float acc = b1[j];
#pragma unroll 8
    for (int d = 0; d < DMODEL; ++d)
        acc = fmaf(pooled[b * DMODEL + d], w1[j * DMODEL + d], acc);
    float r = gelu_f(acc) * w2[j];
#pragma unroll
    for (int o = 32; o > 0; o >>= 1) r += __shfl_down(r, o, 64);
    int lane = j & 63, wid = j >> 6;
    if (lane == 0) red[wid] = r;
    __syncthreads();
    if (j == 0) out[b] = red[0] + red[1] + b2[0];
}

extern "C" void kernel_launch(void* const* d_in, const int* in_sizes, int n_in,
                              void* d_out, int out_size, void* d_ws, size_t ws_size,
                              hipStream_t stream) {
    const float* x         = (const float*)d_in[0];
    const float* conv1_w   = (const float*)d_in[1];
    const float* conv1_b   = (const float*)d_in[2];
    const float* conv2_w   = (const float*)d_in[3];
    const float* conv2_b   = (const float*)d_in[4];
    const float* in_proj_w = (const float*)d_in[5];
    const float* dw_w      = (const float*)d_in[6];
    const float* dw_b      = (const float*)d_in[7];
    const float* dt_bias   = (const float*)d_in[8];
    const float* A_log     = (const float*)d_in[9];
    const float* ssm_D     = (const float*)d_in[10];
    const float* rms_w     = (const float*)d_in[11];
    const float* out_proj_w= (const float*)d_in[12];
    const float* ln_w      = (const float*)d_in[13];
    const float* ln_b      = (const float*)d_in[14];
    const float* reg1_w    = (const float*)d_in[15];
    const float* reg1_b    = (const float*)d_in[16];
    const float* reg2_w    = (const float*)d_in[17];
    const float* reg2_b    = (const float*)d_in[18];

    float* ws = (float*)d_ws;
    size_t off = 0;
    float* c1buf  = ws + off; off += (size_t)NB * 64 * L1OUT;       // 1,048,576
    float* hbuf   = ws + off; off += (size_t)NB * LOUT * DMODEL;    // 2,097,152
    float* zx     = ws + off; off += (size_t)NB * LOUT * DINPROJ;   // 17,956,864
    float* xbcc   = ws + off; off += (size_t)NB * LOUT * CONVDIM;   // 9,437,184
    float* dadt   = ws + off; off += (size_t)NB * LOUT * NHEADS * 2;// 262,144
    float* yss    = ws + off; off += (size_t)NB * LOUT * DINNER;    // 8,388,608
    float* pooled = ws + off; off += NB * DMODEL;                   // 2,048

    f16* fbase = (f16*)(ws + off);
    size_t foff = 0;
    f16* hbf0   = fbase + foff; foff += (size_t)NB * LOUT * DMODEL;
    f16* hbf1   = fbase + foff; foff += (size_t)NB * LOUT * DMODEL;
    f16* ygate  = fbase + foff; foff += (size_t)NB * LOUT * DINNER;
    f16* w_in_h = fbase + foff; foff += (size_t)NLAYERS * NPADIN * DMODEL;
    f16* w_out_h= fbase + foff; foff += (size_t)NLAYERS * DMODEL * DINNER;
    f16* w_c2_h = fbase + foff; foff += (size_t)DMODEL * 1024;
    f16* im2h   = (f16*)yss;   // aliased: im2col dead before yss is first written

    // weight casts
    k_cast_inproj<<<(NLAYERS * NPADIN * 256) / 256, 256, 0, stream>>>(in_proj_w, w_in_h);
    k_cast<<<(NLAYERS * DMODEL * DINNER) / 256, 256, 0, stream>>>(
        out_proj_w, w_out_h, NLAYERS * DMODEL * DINNER);
    k_cast<<<(DMODEL * 1024) / 256, 256, 0, stream>>>(conv2_w, w_c2_h, DMODEL * 1024);

    // front-end convs
    k_conv1<<<(NB * 64 * L1OUT) / 256, 256, 0, stream>>>(x, conv1_w, conv1_b, c1buf);
    k_im2col<<<(NB * LOUT * 1024) / 256, 256, 0, stream>>>(c1buf, im2h);
    {
        dim3 g(256 / 128, 8192 / 64);
        k_hgemm<64, 1><<<g, 256, 0, stream>>>(im2h, w_c2_h, nullptr, hbf0,
                                              8192, 256, 1024, conv2_b);
    }

    f16* hcur = hbf0;
    f16* hnxt = hbf1;
    for (int i = 0; i < NLAYERS; ++i) {
        {
            dim3 g(NPADIN / 128, 8192 / 128);
            k_hgemm<128, 0><<<g, 256, 0, stream>>>(
                hcur, w_in_h + (size_t)i * NPADIN * DMODEL, zx, nullptr,
                8192, DINPROJ, DMODEL, nullptr);
        }
        k_dwconv<<<(NB * LOUT * CONVDIM) / 256, 256, 0, stream>>>(
            zx, dw_w + (size_t)i * CONVDIM * 4, dw_b + (size_t)i * CONVDIM, xbcc);
        k_dt<<<(NB * LOUT * NHEADS) / 256, 256, 0, stream>>>(
            zx, dt_bias + i * NHEADS, A_log + i * NHEADS, dadt);
        k_scan<<<NB * NHEADS * 8, 64, 0, stream>>>(xbcc, dadt, yss);
        k_gate<<<NB * LOUT, 256, 0, stream>>>(zx, xbcc, ssm_D + i * NHEADS,
                                              rms_w + (size_t)i * DINNER, yss, ygate);
        {
            dim3 g(DMODEL / 128, 8192 / 64);
            k_hgemm<64, 0><<<g, 256, 0, stream>>>(
                ygate, w_out_h + (size_t)i * DMODEL * DINNER, hbuf, hnxt,
                8192, DMODEL, DINNER, nullptr);
        }
        f16* tmp = hcur; hcur = hnxt; hnxt = tmp;
    }

    // final LN + pool + head
    k_zero<<<(NB * DMODEL + 255) / 256, 256, 0, stream>>>(pooled, NB * DMODEL);
    k_lnpool<<<NB * LOUT, 256, 0, stream>>>(hbuf, ln_w, ln_b, pooled);
    k_head<<<NB, 128, 0, stream>>>(pooled, reg1_w, reg1_b, reg2_w, reg2_b, (float*)d_out);
}